// Round 6
// baseline (2348.682 us; speedup 1.0000x reference)
//
#include <hip/hip_runtime.h>
#include <math.h>

#define NS 16
#define NC 4
#define NH 256
#define BATCH 262144
#define EPB 16      // elements per block
#define HSTR 264    // LDS row stride in halves (528 B)

// XOR swizzle: row-dependent 16B-granule shift (G4 fix for b128 col reads)
#define LOFF(r, c) ((r) * HSTR + ((c) ^ (((r) & 7) << 3)))

typedef _Float16 half8 __attribute__((ext_vector_type(8)));
typedef _Float16 half4v __attribute__((ext_vector_type(4)));
typedef float f32x4 __attribute__((ext_vector_type(4)));

#define MFMA16(a, b, c) __builtin_amdgcn_mfma_f32_16x16x32_f16((a), (b), (c), 0, 0, 0)

// ---------- ws layout (in halves) ----------
#define OFF_W2HI   0
#define OFF_W2LO   65536
#define OFF_W3HI   131072
#define OFF_W3LO   196608
#define OFF_W2THI  262144
#define OFF_W2TLO  327680
#define OFF_W3THI  393216
#define OFF_W3TLO  458752
#define OFF_W1PHI  524288
#define OFF_W1PLO  532480
#define OFF_W1THI  540672
#define OFF_W1TLO  544768
#define OFF_W4HI   548864
#define OFF_W4LO   552960
#define WS_HALVES  557056   // * 2 bytes = 1,114,112

__device__ __forceinline__ float logsigf(float a) {
    return fminf(a, 0.f) - __logf(1.f + __expf(-fabsf(a)));
}
__device__ __forceinline__ float siggf(float a) {   // sigma(-a)
    return 1.f / (1.f + __expf(a));
}
__device__ __forceinline__ void split2(float x, _Float16& h, _Float16& l) {
    h = (_Float16)x;
    l = (_Float16)(x - (float)h);
}
__device__ __forceinline__ float wsum16(float v) {
    v += __shfl_xor(v, 1, 64);
    v += __shfl_xor(v, 2, 64);
    v += __shfl_xor(v, 4, 64);
    v += __shfl_xor(v, 8, 64);
    return v;
}

// ---------------- prep kernels ----------------
extern "C" __global__ void __launch_bounds__(256)
prep_big(const float* __restrict__ W2, const float* __restrict__ W3,
         _Float16* __restrict__ ws) {
    const int mat = blockIdx.y;
    const float* W = mat ? W3 : W2;
    _Float16* Whi  = ws + (mat ? OFF_W3HI  : OFF_W2HI);
    _Float16* Wlo  = Whi + 65536;
    _Float16* WThi = ws + (mat ? OFF_W3THI : OFF_W2THI);
    _Float16* WTlo = WThi + 65536;
    const int r = blockIdx.x, c = threadIdx.x;
    float x = W[r * NH + c];
    _Float16 h, l; split2(x, h, l);
    Whi[r * NH + c] = h;  Wlo[r * NH + c] = l;
    WThi[c * NH + r] = h; WTlo[c * NH + r] = l;
}

extern "C" __global__ void __launch_bounds__(256)
prep_small(const float* __restrict__ W1, const float* __restrict__ W4,
           _Float16* __restrict__ ws) {
    _Float16* W1phi = ws + OFF_W1PHI;
    _Float16* W1plo = ws + OFF_W1PLO;
    _Float16* W1Thi = ws + OFF_W1THI;
    _Float16* W1Tlo = ws + OFF_W1TLO;
    _Float16* W4hi  = ws + OFF_W4HI;
    _Float16* W4lo  = ws + OFF_W4LO;
    const int t = threadIdx.x;   // 0..255 (= W1 row)
    #pragma unroll
    for (int s = 0; s < NS; s++) {
        float x = W1[t * NS + s];
        _Float16 h, l; split2(x, h, l);
        W1phi[t * 32 + s] = h;        W1plo[t * 32 + s] = l;
        W1phi[t * 32 + 16 + s] = (_Float16)0.f;
        W1plo[t * 32 + 16 + s] = (_Float16)0.f;
        W1Thi[s * NH + t] = h;        W1Tlo[s * NH + t] = l;
    }
    #pragma unroll
    for (int q = 0; q < 16; q++) {
        int idx = q * 256 + t;       // covers rows 0..15 of W4
        float x = W4[idx];
        _Float16 h, l; split2(x, h, l);
        W4hi[idx] = h; W4lo[idx] = l;
    }
}

// ---------------- main fused MFMA kernel ----------------
// 256 threads = 4 waves, EPB=16. Wave w owns hidden rows 64w..64w+63
// (4 m-tiles). Forward N=16 (1 n-tile). Backward: ONE pass, 64 cotangent
// cols (4 n-tiles). H (16 x HSTR) aliases M (64 x HSTR). LDS = 76,160 B
// -> 2 independent blocks/CU. XOR-swizzled LDS (LOFF) for conflict-free
// b128 column reads.

__device__ __forceinline__ void gemm_fwd(const _Float16* __restrict__ Ahi,
                                         const _Float16* __restrict__ Alo,
                                         const _Float16* Bh, const _Float16* Bl,
                                         int w, int lo16, int hi4, f32x4 acc[4]) {
    #pragma unroll
    for (int ks = 0; ks < 8; ks++) {
        int boff = LOFF(lo16, ks * 32 + hi4 * 8);
        half8 bh = *(const half8*)&Bh[boff];
        half8 bl = *(const half8*)&Bl[boff];
        #pragma unroll
        for (int m = 0; m < 4; m++) {
            int woff = (64 * w + 16 * m + lo16) * NH + ks * 32 + hi4 * 8;
            half8 ah = *(const half8*)&Ahi[woff];
            half8 al = *(const half8*)&Alo[woff];
            acc[m] = MFMA16(ah, bh, acc[m]);
            acc[m] = MFMA16(al, bh, acc[m]);
            acc[m] = MFMA16(ah, bl, acc[m]);
        }
    }
}

__device__ __forceinline__ void gemm_bwd(const _Float16* __restrict__ Ahi,
                                         const _Float16* __restrict__ Alo,
                                         const _Float16* Bh, const _Float16* Bl,
                                         int w, int lo16, int hi4, f32x4 acc[4][4]) {
    #pragma unroll
    for (int ks = 0; ks < 8; ks++) {
        half8 bh[4], bl[4];
        #pragma unroll
        for (int n = 0; n < 4; n++) {
            int off = LOFF(16 * n + lo16, ks * 32 + hi4 * 8);
            bh[n] = *(const half8*)&Bh[off];
            bl[n] = *(const half8*)&Bl[off];
        }
        #pragma unroll
        for (int m = 0; m < 4; m++) {
            int woff = (64 * w + 16 * m + lo16) * NH + ks * 32 + hi4 * 8;
            half8 ah = *(const half8*)&Ahi[woff];
            half8 al = *(const half8*)&Alo[woff];
            #pragma unroll
            for (int n = 0; n < 4; n++) {
                acc[m][n] = MFMA16(ah, bh[n], acc[m][n]);
                acc[m][n] = MFMA16(al, bh[n], acc[m][n]);
                acc[m][n] = MFMA16(ah, bl[n], acc[m][n]);
            }
        }
    }
}

__global__ void __launch_bounds__(256, 2)
comet_mfma(const float* __restrict__ Z,
           const float* __restrict__ W4,
           const _Float16* __restrict__ ws,
           float* __restrict__ OUT)
{
    const _Float16* W2hi  = ws + OFF_W2HI;
    const _Float16* W2lo  = ws + OFF_W2LO;
    const _Float16* W3hi  = ws + OFF_W3HI;
    const _Float16* W3lo  = ws + OFF_W3LO;
    const _Float16* W2Thi = ws + OFF_W2THI;
    const _Float16* W2Tlo = ws + OFF_W2TLO;
    const _Float16* W3Thi = ws + OFF_W3THI;
    const _Float16* W3Tlo = ws + OFF_W3TLO;
    const _Float16* W1phi = ws + OFF_W1PHI;
    const _Float16* W1plo = ws + OFF_W1PLO;
    const _Float16* W1Thi = ws + OFF_W1THI;
    const _Float16* W1Tlo = ws + OFF_W1TLO;
    const _Float16* W4hi  = ws + OFF_W4HI;
    const _Float16* W4lo  = ws + OFF_W4LO;

    // union: H = rows 0..15 (forward, by elem), M = rows 0..63 (backward, by col)
    __shared__ __align__(16) _Float16 U0[64 * HSTR];   // 33,792 B
    __shared__ __align__(16) _Float16 U1[64 * HSTR];   // 33,792 B
    __shared__ __align__(16) float Jfin[16 * 66];      //  4,224 B
    __shared__ __align__(16) float Db[4 * 16 * 17];    //  4,352 B

    const int tid  = threadIdx.x;
    const int l    = tid & 63, w = tid >> 6;
    const int lo16 = l & 15, hi4 = l >> 4;
    const int ebase = blockIdx.x * EPB;
    const int c4 = lo16 & 3;

    // ---- V (rows 16..19 of W4) in registers ----
    float4 vreg[4];
    #pragma unroll
    for (int m = 0; m < 4; m++)
        vreg[m] = *(const float4*)&W4[(NS + c4) * NH + 64 * w + 16 * m + 4 * hi4];

    float g1[4][4], g2f[4][4], g3f[4][4];   // [m][r], forward gate sigma(-a)

    // ---- F1 : a1 = W1p @ Zpad ; B-frag direct from global ----
    {
        f32x4 acc[4];
        #pragma unroll
        for (int m = 0; m < 4; m++) acc[m] = (f32x4)(0.f);
        half8 bh, bl;
        if (hi4 < 2) {
            const float* zp = &Z[(size_t)(ebase + lo16) * NS + hi4 * 8];
            float4 z0 = *(const float4*)zp;
            float4 z1 = *(const float4*)(zp + 4);
            float zz[8] = {z0.x, z0.y, z0.z, z0.w, z1.x, z1.y, z1.z, z1.w};
            #pragma unroll
            for (int r = 0; r < 8; r++) {
                _Float16 h, lo; split2(zz[r], h, lo);
                bh[r] = h; bl[r] = lo;
            }
        } else {
            #pragma unroll
            for (int r = 0; r < 8; r++) { bh[r] = (_Float16)0.f; bl[r] = (_Float16)0.f; }
        }
        #pragma unroll
        for (int m = 0; m < 4; m++) {
            int woff = (64 * w + 16 * m + lo16) * 32 + hi4 * 8;
            half8 ah = *(const half8*)&W1phi[woff];
            half8 al = *(const half8*)&W1plo[woff];
            acc[m] = MFMA16(ah, bh, acc[m]);
            acc[m] = MFMA16(al, bh, acc[m]);
            acc[m] = MFMA16(ah, bl, acc[m]);
        }
        #pragma unroll
        for (int m = 0; m < 4; m++) {
            int hoff = LOFF(lo16, 64 * w + 16 * m + 4 * hi4);
            half4v nh, nl;
            #pragma unroll
            for (int r = 0; r < 4; r++) {
                float a = acc[m][r];
                g1[m][r] = siggf(a);
                float hv = logsigf(a);
                _Float16 xh, xl; split2(hv, xh, xl);
                nh[r] = xh; nl[r] = xl;
            }
            *(half4v*)&U0[hoff] = nh;
            *(half4v*)&U1[hoff] = nl;
        }
    }
    __syncthreads();

    // ---- F2, F3 ----
    #pragma unroll
    for (int L = 0; L < 2; L++) {
        f32x4 acc[4];
        #pragma unroll
        for (int m = 0; m < 4; m++) acc[m] = (f32x4)(0.f);
        gemm_fwd(L ? W3hi : W2hi, L ? W3lo : W2lo, U0, U1, w, lo16, hi4, acc);
        __syncthreads();   // all reads of H done before update
        #pragma unroll
        for (int m = 0; m < 4; m++) {
            int hoff = LOFF(lo16, 64 * w + 16 * m + 4 * hi4);
            half4v oh = *(const half4v*)&U0[hoff];
            half4v ol = *(const half4v*)&U1[hoff];
            half4v nh, nl;
            #pragma unroll
            for (int r = 0; r < 4; r++) {
                float a = acc[m][r];
                float g = siggf(a);
                if (L) g3f[m][r] = g; else g2f[m][r] = g;
                float hv = (float)oh[r] + (float)ol[r] + logsigf(a);
                _Float16 xh, xl; split2(hv, xh, xl);
                nh[r] = xh; nl[r] = xl;
            }
            *(half4v*)&U0[hoff] = nh;
            *(half4v*)&U1[hoff] = nl;
        }
        __syncthreads();
    }

    // ---- F4 : d = W4[0:16] @ h3 ; 4-way split-K, write Db[w][s][e] ----
    {
        f32x4 acc = (f32x4)(0.f);
        #pragma unroll
        for (int i = 0; i < 2; i++) {
            int ks = 2 * w + i;
            int boff = LOFF(lo16, ks * 32 + hi4 * 8);
            half8 bh = *(const half8*)&U0[boff];
            half8 bl = *(const half8*)&U1[boff];
            int woff = lo16 * NH + ks * 32 + hi4 * 8;
            half8 ah = *(const half8*)&W4hi[woff];
            half8 al = *(const half8*)&W4lo[woff];
            acc = MFMA16(ah, bh, acc);
            acc = MFMA16(al, bh, acc);
            acc = MFMA16(ah, bl, acc);
        }
        #pragma unroll
        for (int r = 0; r < 4; r++)
            Db[w * 272 + (4 * hi4 + r) * 17 + lo16] = acc[r];
    }
    __syncthreads();   // H (union) dead; M may be written

    // ---- backward: single pass, 64 cotangent cols (4 n-tiles) ----
    // m3 = V .* d3
    #pragma unroll
    for (int m = 0; m < 4; m++)
        #pragma unroll
        for (int n = 0; n < 4; n++) {
            const int src = (l & 48) | (4 * n + (lo16 >> 2));
            half4v vh, vl;
            #pragma unroll
            for (int r = 0; r < 4; r++) {
                float g = __shfl(g3f[m][r], src, 64);
                float val = vreg[m][r] * g;
                _Float16 xh, xl; split2(val, xh, xl);
                vh[r] = xh; vl[r] = xl;
            }
            int moff = LOFF(16 * n + lo16, 64 * w + 16 * m + 4 * hi4);
            *(half4v*)&U0[moff] = vh;
            *(half4v*)&U1[moff] = vl;
        }
    __syncthreads();

    // B3: G2 = W3^T @ m3
    f32x4 acc2[4][4];
    #pragma unroll
    for (int m = 0; m < 4; m++)
        #pragma unroll
        for (int n = 0; n < 4; n++) acc2[m][n] = (f32x4)(0.f);
    gemm_bwd(W3Thi, W3Tlo, U0, U1, w, lo16, hi4, acc2);
    __syncthreads();   // readers of m3 done

    // g2 = V + G2 ; m2 = g2 .* d2 ; keep g2 in acc2
    #pragma unroll
    for (int m = 0; m < 4; m++)
        #pragma unroll
        for (int n = 0; n < 4; n++) {
            const int src = (l & 48) | (4 * n + (lo16 >> 2));
            half4v vh, vl;
            #pragma unroll
            for (int r = 0; r < 4; r++) {
                float gg2 = vreg[m][r] + acc2[m][n][r];
                acc2[m][n][r] = gg2;
                float g = __shfl(g2f[m][r], src, 64);
                _Float16 xh, xl; split2(gg2 * g, xh, xl);
                vh[r] = xh; vl[r] = xl;
            }
            int moff = LOFF(16 * n + lo16, 64 * w + 16 * m + 4 * hi4);
            *(half4v*)&U0[moff] = vh;
            *(half4v*)&U1[moff] = vl;
        }
    __syncthreads();

    // B2: g1tot = g2 + W2^T @ m2   (accumulate onto acc2)
    gemm_bwd(W2Thi, W2Tlo, U0, U1, w, lo16, hi4, acc2);
    __syncthreads();

    // m1 = g1tot .* d1
    #pragma unroll
    for (int m = 0; m < 4; m++)
        #pragma unroll
        for (int n = 0; n < 4; n++) {
            const int src = (l & 48) | (4 * n + (lo16 >> 2));
            half4v vh, vl;
            #pragma unroll
            for (int r = 0; r < 4; r++) {
                float g = __shfl(g1[m][r], src, 64);
                _Float16 xh, xl; split2(acc2[m][n][r] * g, xh, xl);
                vh[r] = xh; vl[r] = xl;
            }
            int moff = LOFF(16 * n + lo16, 64 * w + 16 * m + 4 * hi4);
            *(half4v*)&U0[moff] = vh;
            *(half4v*)&U1[moff] = vl;
        }
    __syncthreads();

    // J = W1^T @ m1 ; wave w owns n-tile w, full K
    {
        f32x4 accj = (f32x4)(0.f);
        #pragma unroll
        for (int ks = 0; ks < 8; ks++) {
            int boff = LOFF(16 * w + lo16, ks * 32 + hi4 * 8);
            half8 bh = *(const half8*)&U0[boff];
            half8 bl = *(const half8*)&U1[boff];
            int woff = lo16 * NH + ks * 32 + hi4 * 8;
            half8 ah = *(const half8*)&W1Thi[woff];
            half8 al = *(const half8*)&W1Tlo[woff];
            accj = MFMA16(ah, bh, accj);
            accj = MFMA16(al, bh, accj);
            accj = MFMA16(ah, bl, accj);
        }
        #pragma unroll
        for (int r = 0; r < 4; r++)
            Jfin[(4 * hi4 + r) * 66 + 16 * w + lo16] = accj[r];
    }
    __syncthreads();

    // ---- projection: e = 4w + hi4, s = lo16 ----
    {
        const int e = 4 * w + hi4, s = lo16;
        float acol[4];
        #pragma unroll
        for (int c = 0; c < 4; c++) acol[c] = Jfin[s * 66 + 4 * e + c];
        float dval = 0.f;
        #pragma unroll
        for (int q = 0; q < 4; q++) dval += Db[q * 272 + s * 17 + e];
        #pragma unroll
        for (int c = 0; c < 4; c++) {
            float n2 = wsum16(acol[c] * acol[c]);
            float inv = (n2 > 1e-30f) ? (1.0f / sqrtf(n2)) : 0.0f;
            float q = acol[c] * inv;
            #pragma unroll
            for (int cc = c + 1; cc < 4; cc++) {
                float pj = wsum16(acol[cc] * q);
                acol[cc] -= pj * q;
            }
            float pd = wsum16(dval * q);
            dval -= pd * q;
        }
        OUT[(size_t)(ebase + e) * NS + s] = dval;
    }
}

// ---------------- f32 fallback (round-1 kernel) ----------------
__device__ __forceinline__ float dot4f(float4 a, float4 b) {
    return a.x*b.x + a.y*b.y + a.z*b.z + a.w*b.w;
}

__global__ void __launch_bounds__(256, 2)
comet_fused_f32(const float* __restrict__ Z,
                const float* __restrict__ W1,
                const float* __restrict__ W2,
                const float* __restrict__ W3,
                const float* __restrict__ W4,
                float* __restrict__ OUT)
{
    __shared__ __align__(16) float h_lds[4][4][NH];
    __shared__ __align__(16) float m_lds[4][4][NH][NC];

    const int l = threadIdx.x & 63;
    const int w = threadIdx.x >> 6;
    float (*hb)[NH]     = h_lds[w];
    float (*mb)[NH][NC] = m_lds[w];
    const int ebase = (blockIdx.x * 4 + w) * 4;

    float d1g[4][4], d2g[4][4], d3g[4][4];

    {
        float acc[4][4];
        #pragma unroll
        for (int j = 0; j < 4; j++)
            #pragma unroll
            for (int e = 0; e < 4; e++) acc[j][e] = 0.f;
        #pragma unroll
        for (int s4 = 0; s4 < 4; s4++) {
            float4 wf[4];
            #pragma unroll
            for (int j = 0; j < 4; j++)
                wf[j] = *(const float4*)&W1[(l + 64*j) * NS + s4*4];
            #pragma unroll
            for (int e = 0; e < 4; e++) {
                float4 xv = *(const float4*)&Z[(ebase + e) * NS + s4*4];
                #pragma unroll
                for (int j = 0; j < 4; j++) acc[j][e] += dot4f(wf[j], xv);
            }
        }
        #pragma unroll
        for (int j = 0; j < 4; j++)
            #pragma unroll
            for (int e = 0; e < 4; e++) {
                float a = acc[j][e];
                d1g[j][e] = siggf(a);
                hb[e][l + 64*j] = logsigf(a);
            }
    }
    __syncthreads();

#define FWD_LAYER(WPTR, GARR)                                                   \
    {                                                                           \
        float acc[4][4];                                                        \
        _Pragma("unroll")                                                       \
        for (int j = 0; j < 4; j++) {                                           \
            _Pragma("unroll")                                                   \
            for (int e = 0; e < 4; e++) acc[j][e] = 0.f;                        \
        }                                                                       \
        _Pragma("unroll 2")                                                     \
        for (int kk = 0; kk < NH; kk += 4) {                                    \
            float wv[4][4];                                                     \
            _Pragma("unroll")                                                   \
            for (int j = 0; j < 4; j++) {                                       \
                float4 t = *(const float4*)&WPTR[(l + 64*j) * NH + kk];         \
                wv[0][j] = t.x; wv[1][j] = t.y; wv[2][j] = t.z; wv[3][j] = t.w; \
            }                                                                   \
            _Pragma("unroll")                                                   \
            for (int e = 0; e < 4; e++) {                                       \
                float4 hv = *(const float4*)&hb[e][kk];                         \
                _Pragma("unroll")                                               \
                for (int j = 0; j < 4; j++)                                     \
                    acc[j][e] += wv[0][j]*hv.x + wv[1][j]*hv.y                  \
                               + wv[2][j]*hv.z + wv[3][j]*hv.w;                 \
            }                                                                   \
        }                                                                       \
        __syncthreads();                                                        \
        _Pragma("unroll")                                                       \
        for (int j = 0; j < 4; j++) {                                           \
            _Pragma("unroll")                                                   \
            for (int e = 0; e < 4; e++) {                                       \
                float a = acc[j][e];                                            \
                GARR[j][e] = siggf(a);                                          \
                hb[e][l + 64*j] += logsigf(a);                                  \
            }                                                                   \
        }                                                                       \
        __syncthreads();                                                        \
    }

    FWD_LAYER(W2, d2g)
    FWD_LAYER(W3, d3g)
#undef FWD_LAYER

    const int e4 = l >> 4, s4 = l & 15;
    float dval = 0.f;
    {
        #pragma unroll 2
        for (int kk = 0; kk < NH; kk += 4) {
            float4 wf = *(const float4*)&W4[s4 * NH + kk];
            float4 hv = *(const float4*)&hb[e4][kk];
            dval += dot4f(wf, hv);
        }
    }

    float gacc[4][4][4];
    float vf[4][4];
    #pragma unroll
    for (int c = 0; c < 4; c++)
        #pragma unroll
        for (int j = 0; j < 4; j++)
            vf[c][j] = W4[(NS + c) * NH + l + 64*j];
    #pragma unroll
    for (int e = 0; e < 4; e++)
        #pragma unroll
        for (int c = 0; c < 4; c++)
            #pragma unroll
            for (int j = 0; j < 4; j++)
                gacc[e][c][j] = vf[c][j];
    #pragma unroll
    for (int j = 0; j < 4; j++)
        #pragma unroll
        for (int e = 0; e < 4; e++) {
            float g = d3g[j][e];
            float4 mv = make_float4(vf[0][j]*g, vf[1][j]*g, vf[2][j]*g, vf[3][j]*g);
            *(float4*)&mb[e][l + 64*j][0] = mv;
        }
    __syncthreads();

#define BWD_GEMM(WPTR)                                                          \
    {                                                                           \
        _Pragma("unroll 2")                                                     \
        for (int r = 0; r < NH; r++) {                                          \
            float wc[4];                                                        \
            _Pragma("unroll")                                                   \
            for (int j = 0; j < 4; j++) wc[j] = WPTR[r * NH + l + 64*j];        \
            _Pragma("unroll")                                                   \
            for (int e = 0; e < 4; e++) {                                       \
                float4 mv = *(const float4*)&mb[e][r][0];                       \
                _Pragma("unroll")                                               \
                for (int j = 0; j < 4; j++) {                                   \
                    gacc[e][0][j] += wc[j]*mv.x;                                \
                    gacc[e][1][j] += wc[j]*mv.y;                                \
                    gacc[e][2][j] += wc[j]*mv.z;                                \
                    gacc[e][3][j] += wc[j]*mv.w;                                \
                }                                                               \
            }                                                                   \
        }                                                                       \
    }

    BWD_GEMM(W3)
    __syncthreads();
    #pragma unroll
    for (int j = 0; j < 4; j++)
        #pragma unroll
        for (int e = 0; e < 4; e++) {
            float g = d2g[j][e];
            float4 mv = make_float4(gacc[e][0][j]*g, gacc[e][1][j]*g,
                                    gacc[e][2][j]*g, gacc[e][3][j]*g);
            *(float4*)&mb[e][l + 64*j][0] = mv;
        }
    __syncthreads();
    BWD_GEMM(W2)
#undef BWD_GEMM
    __syncthreads();
    #pragma unroll
    for (int j = 0; j < 4; j++)
        #pragma unroll
        for (int e = 0; e < 4; e++) {
            float g = d1g[j][e];
            float4 mv = make_float4(gacc[e][0][j]*g, gacc[e][1][j]*g,
                                    gacc[e][2][j]*g, gacc[e][3][j]*g);
            *(float4*)&mb[e][l + 64*j][0] = mv;
        }
    __syncthreads();

    const int c4 = l >> 4;
    float jv[4] = {0.f, 0.f, 0.f, 0.f};
    #pragma unroll 4
    for (int r = 0; r < NH; r++) {
        float w1v = W1[r * NS + s4];
        #pragma unroll
        for (int e = 0; e < 4; e++) jv[e] += mb[e][r][c4] * w1v;
    }
    __syncthreads();

    float* jlds = (float*)hb;
    #pragma unroll
    for (int e = 0; e < 4; e++) jlds[e * 64 + c4 * 16 + s4] = jv[e];
    __syncthreads();

    float acol[4];
    acol[0] = jlds[e4 * 64 +      s4];
    acol[1] = jlds[e4 * 64 + 16 + s4];
    acol[2] = jlds[e4 * 64 + 32 + s4];
    acol[3] = jlds[e4 * 64 + 48 + s4];
    #pragma unroll
    for (int c = 0; c < 4; c++) {
        float n2 = wsum16(acol[c] * acol[c]);
        float inv = (n2 > 1e-30f) ? (1.0f / sqrtf(n2)) : 0.0f;
        float q = acol[c] * inv;
        #pragma unroll
        for (int cc = c + 1; cc < 4; cc++) {
            float p = wsum16(acol[cc] * q);
            acol[cc] -= p * q;
        }
        float pd = wsum16(dval * q);
        dval -= pd * q;
    }
    OUT[ebase * NS + l] = dval;
}

extern "C" void kernel_launch(void* const* d_in, const int* in_sizes, int n_in,
                              void* d_out, int out_size, void* d_ws, size_t ws_size,
                              hipStream_t stream) {
    const float* Z  = (const float*)d_in[0];
    const float* W1 = (const float*)d_in[1];
    const float* W2 = (const float*)d_in[2];
    const float* W3 = (const float*)d_in[3];
    const float* W4 = (const float*)d_in[4];
    float* OUT = (float*)d_out;

    const size_t need = (size_t)WS_HALVES * sizeof(_Float16);

    if (ws_size >= need) {
        _Float16* ws = (_Float16*)d_ws;
        hipLaunchKernelGGL(prep_big, dim3(NH, 2), dim3(NH), 0, stream, W2, W3, ws);
        hipLaunchKernelGGL(prep_small, dim3(1), dim3(NH), 0, stream, W1, W4, ws);
        hipLaunchKernelGGL(comet_mfma, dim3(BATCH / EPB), dim3(256), 0, stream,
                           Z, W4, ws, OUT);
    } else {
        hipLaunchKernelGGL(comet_fused_f32, dim3(BATCH / 16), dim3(256), 0, stream,
                           Z, W1, W2, W3, W4, OUT);
    }
}

// Round 7
// 1434.607 us; speedup vs baseline: 1.6372x; 1.6372x over previous
//
#include <hip/hip_runtime.h>
#include <math.h>

#define NS 16
#define NC 4
#define NH 256
#define BATCH 262144
#define EPB 32      // elements per block
#define HSTR 264    // LDS row stride in halves (528 B); 264/2 mod 32 = 4 bank-words
                    // per row -> natural 2-way (free) rotation. DO NOT swizzle (R6).

typedef _Float16 half8 __attribute__((ext_vector_type(8)));
typedef _Float16 half4v __attribute__((ext_vector_type(4)));
typedef float f32x4 __attribute__((ext_vector_type(4)));

#define MFMA16(a, b, c) __builtin_amdgcn_mfma_f32_16x16x32_f16((a), (b), (c), 0, 0, 0)

// ---------- ws layout (in halves) ----------
#define OFF_W2HI   0
#define OFF_W2LO   65536
#define OFF_W3HI   131072
#define OFF_W3LO   196608
#define OFF_W2THI  262144
#define OFF_W2TLO  327680
#define OFF_W3THI  393216
#define OFF_W3TLO  458752
#define OFF_W1PHI  524288
#define OFF_W1PLO  532480
#define OFF_W1THI  540672
#define OFF_W1TLO  544768
#define OFF_W4HI   548864
#define OFF_W4LO   552960
#define WS_HALVES  557056   // * 2 bytes = 1,114,112

__device__ __forceinline__ float logsigf(float a) {
    return fminf(a, 0.f) - __logf(1.f + __expf(-fabsf(a)));
}
__device__ __forceinline__ float siggf(float a) {   // sigma(-a)
    return 1.f / (1.f + __expf(a));
}
__device__ __forceinline__ void split2(float x, _Float16& h, _Float16& l) {
    h = (_Float16)x;
    l = (_Float16)(x - (float)h);
}
__device__ __forceinline__ float wsum16(float v) {
    v += __shfl_xor(v, 1, 64);
    v += __shfl_xor(v, 2, 64);
    v += __shfl_xor(v, 4, 64);
    v += __shfl_xor(v, 8, 64);
    return v;
}

// ---------------- prep kernels ----------------
extern "C" __global__ void __launch_bounds__(256)
prep_big(const float* __restrict__ W2, const float* __restrict__ W3,
         _Float16* __restrict__ ws) {
    const int mat = blockIdx.y;
    const float* W = mat ? W3 : W2;
    _Float16* Whi  = ws + (mat ? OFF_W3HI  : OFF_W2HI);
    _Float16* Wlo  = Whi + 65536;
    _Float16* WThi = ws + (mat ? OFF_W3THI : OFF_W2THI);
    _Float16* WTlo = WThi + 65536;
    const int r = blockIdx.x, c = threadIdx.x;
    float x = W[r * NH + c];
    _Float16 h, l; split2(x, h, l);
    Whi[r * NH + c] = h;  Wlo[r * NH + c] = l;
    WThi[c * NH + r] = h; WTlo[c * NH + r] = l;
}

extern "C" __global__ void __launch_bounds__(256)
prep_small(const float* __restrict__ W1, const float* __restrict__ W4,
           _Float16* __restrict__ ws) {
    _Float16* W1phi = ws + OFF_W1PHI;
    _Float16* W1plo = ws + OFF_W1PLO;
    _Float16* W1Thi = ws + OFF_W1THI;
    _Float16* W1Tlo = ws + OFF_W1TLO;
    _Float16* W4hi  = ws + OFF_W4HI;
    _Float16* W4lo  = ws + OFF_W4LO;
    const int t = threadIdx.x;   // 0..255 (= W1 row)
    #pragma unroll
    for (int s = 0; s < NS; s++) {
        float x = W1[t * NS + s];
        _Float16 h, l; split2(x, h, l);
        W1phi[t * 32 + s] = h;        W1plo[t * 32 + s] = l;
        W1phi[t * 32 + 16 + s] = (_Float16)0.f;
        W1plo[t * 32 + 16 + s] = (_Float16)0.f;
        W1Thi[s * NH + t] = h;        W1Tlo[s * NH + t] = l;
    }
    #pragma unroll
    for (int q = 0; q < 16; q++) {
        int idx = q * 256 + t;       // covers rows 0..15 of W4
        float x = W4[idx];
        _Float16 h, l; split2(x, h, l);
        W4hi[idx] = h; W4lo[idx] = l;
    }
}

// ---------------- main fused MFMA kernel ----------------
// E=32/block, 512 threads = 8 waves. Wave w owns hidden rows 32w..32w+31
// (2 m-tiles). Forward N=32 (2 e-tiles), 3-term f16-split precision.
// Backward: 2 passes x 16 elems (64 cotangent cols), SINGLE-term f16
// (precision analysis: adds ~1e-3 rel on J, threshold margin 3.6x).
// One LDS union U[64][HSTR]:
//   forward: H-hi rows 0..31 (by elem), H-lo rows 32..63
//   backward: M-hi rows 0..63 (by cotangent col)
// LDS = 44.3 KB -> 2 independent blocks/CU (VGPR ~124 -> 4 waves/SIMD).

__device__ __forceinline__ void gemm_fwd(const _Float16* __restrict__ Ahi,
                                         const _Float16* __restrict__ Alo,
                                         const _Float16* U,
                                         int w, int lo16, int hi4, f32x4 acc[2][2]) {
    const _Float16* Bh = U;
    const _Float16* Bl = U + 32 * HSTR;
    #pragma unroll
    for (int ks = 0; ks < 8; ks++) {
        half8 bh[2], bl[2];
        #pragma unroll
        for (int n = 0; n < 2; n++) {
            int off = (16 * n + lo16) * HSTR + ks * 32 + hi4 * 8;
            bh[n] = *(const half8*)&Bh[off];
            bl[n] = *(const half8*)&Bl[off];
        }
        #pragma unroll
        for (int m = 0; m < 2; m++) {
            int woff = (32 * w + 16 * m + lo16) * NH + ks * 32 + hi4 * 8;
            half8 ah = *(const half8*)&Ahi[woff];
            half8 al = *(const half8*)&Alo[woff];
            #pragma unroll
            for (int n = 0; n < 2; n++) {
                acc[m][n] = MFMA16(ah, bh[n], acc[m][n]);
                acc[m][n] = MFMA16(al, bh[n], acc[m][n]);
                acc[m][n] = MFMA16(ah, bl[n], acc[m][n]);
            }
        }
    }
}

// single-term f16 backward GEMM: A = W^T hi only, B = M hi only
__device__ __forceinline__ void gemm_bwd1(const _Float16* __restrict__ Ahi,
                                          const _Float16* U,
                                          int w, int lo16, int hi4, f32x4 acc[2][4]) {
    #pragma unroll
    for (int ks = 0; ks < 8; ks++) {
        half8 bh[4];
        #pragma unroll
        for (int n = 0; n < 4; n++) {
            int off = (16 * n + lo16) * HSTR + ks * 32 + hi4 * 8;
            bh[n] = *(const half8*)&U[off];
        }
        #pragma unroll
        for (int m = 0; m < 2; m++) {
            int woff = (32 * w + 16 * m + lo16) * NH + ks * 32 + hi4 * 8;
            half8 ah = *(const half8*)&Ahi[woff];
            #pragma unroll
            for (int n = 0; n < 4; n++)
                acc[m][n] = MFMA16(ah, bh[n], acc[m][n]);
        }
    }
}

__global__ void __launch_bounds__(512, 2)
comet_mfma(const float* __restrict__ Z,
           const float* __restrict__ W4,
           const _Float16* __restrict__ ws,
           float* __restrict__ OUT)
{
    const _Float16* W2hi  = ws + OFF_W2HI;
    const _Float16* W2lo  = ws + OFF_W2LO;
    const _Float16* W3hi  = ws + OFF_W3HI;
    const _Float16* W3lo  = ws + OFF_W3LO;
    const _Float16* W2Thi = ws + OFF_W2THI;
    const _Float16* W3Thi = ws + OFF_W3THI;
    const _Float16* W1phi = ws + OFF_W1PHI;
    const _Float16* W1plo = ws + OFF_W1PLO;
    const _Float16* W1Thi = ws + OFF_W1THI;
    const _Float16* W4hi  = ws + OFF_W4HI;
    const _Float16* W4lo  = ws + OFF_W4LO;

    // single union buffer (see header comment)
    __shared__ __align__(16) _Float16 U[64 * HSTR];    // 33,792 B
    __shared__ __align__(16) float Jfin[16 * 130];     //  8,320 B
    __shared__ __align__(16) float Db[32 * 17];        //  2,176 B

    const int tid  = threadIdx.x;
    const int l    = tid & 63, w = tid >> 6;
    const int lo16 = l & 15, hi4 = l >> 4;
    const int ebase = blockIdx.x * EPB;
    const int c4 = lo16 & 3;

    // ---- V (rows 16..19 of W4) in registers: n-independent per lane ----
    float4 vreg[2];
    #pragma unroll
    for (int m = 0; m < 2; m++)
        vreg[m] = *(const float4*)&W4[(NS + c4) * NH + 32 * w + 16 * m + 4 * hi4];

    float g1[2][2][4], g2f[2][2][4], g3f[2][2][4];   // [m][e-tile][r]

    // ---- F1 : a1 = W1p @ Zpad ; B-frag direct from global ----
    {
        f32x4 acc[2][2];
        #pragma unroll
        for (int m = 0; m < 2; m++)
            #pragma unroll
            for (int n = 0; n < 2; n++) acc[m][n] = (f32x4)(0.f);
        half8 bh[2], bl[2];
        #pragma unroll
        for (int n = 0; n < 2; n++) {
            if (hi4 < 2) {
                const float* zp = &Z[(size_t)(ebase + 16 * n + lo16) * NS + hi4 * 8];
                float4 z0 = *(const float4*)zp;
                float4 z1 = *(const float4*)(zp + 4);
                float zz[8] = {z0.x, z0.y, z0.z, z0.w, z1.x, z1.y, z1.z, z1.w};
                #pragma unroll
                for (int r = 0; r < 8; r++) {
                    _Float16 h, lo; split2(zz[r], h, lo);
                    bh[n][r] = h; bl[n][r] = lo;
                }
            } else {
                #pragma unroll
                for (int r = 0; r < 8; r++) { bh[n][r] = (_Float16)0.f; bl[n][r] = (_Float16)0.f; }
            }
        }
        #pragma unroll
        for (int m = 0; m < 2; m++) {
            int woff = (32 * w + 16 * m + lo16) * 32 + hi4 * 8;
            half8 ah = *(const half8*)&W1phi[woff];
            half8 al = *(const half8*)&W1plo[woff];
            #pragma unroll
            for (int n = 0; n < 2; n++) {
                acc[m][n] = MFMA16(ah, bh[n], acc[m][n]);
                acc[m][n] = MFMA16(al, bh[n], acc[m][n]);
                acc[m][n] = MFMA16(ah, bl[n], acc[m][n]);
            }
        }
        #pragma unroll
        for (int m = 0; m < 2; m++)
            #pragma unroll
            for (int n = 0; n < 2; n++) {
                int hoff = (16 * n + lo16) * HSTR + 32 * w + 16 * m + 4 * hi4;
                half4v nh, nl;
                #pragma unroll
                for (int r = 0; r < 4; r++) {
                    float a = acc[m][n][r];
                    g1[m][n][r] = siggf(a);
                    float hv = logsigf(a);
                    _Float16 xh, xl; split2(hv, xh, xl);
                    nh[r] = xh; nl[r] = xl;
                }
                *(half4v*)&U[hoff] = nh;
                *(half4v*)&U[32 * HSTR + hoff] = nl;
            }
    }
    __syncthreads();

    // ---- F2, F3 ----
    #pragma unroll
    for (int L = 0; L < 2; L++) {
        f32x4 acc[2][2];
        #pragma unroll
        for (int m = 0; m < 2; m++)
            #pragma unroll
            for (int n = 0; n < 2; n++) acc[m][n] = (f32x4)(0.f);
        gemm_fwd(L ? W3hi : W2hi, L ? W3lo : W2lo, U, w, lo16, hi4, acc);
        __syncthreads();   // all reads of H done before update
        #pragma unroll
        for (int m = 0; m < 2; m++)
            #pragma unroll
            for (int n = 0; n < 2; n++) {
                int hoff = (16 * n + lo16) * HSTR + 32 * w + 16 * m + 4 * hi4;
                half4v oh = *(const half4v*)&U[hoff];
                half4v ol = *(const half4v*)&U[32 * HSTR + hoff];
                half4v nh, nl;
                #pragma unroll
                for (int r = 0; r < 4; r++) {
                    float a = acc[m][n][r];
                    float g = siggf(a);
                    if (L) g3f[m][n][r] = g; else g2f[m][n][r] = g;
                    float hv = (float)oh[r] + (float)ol[r] + logsigf(a);
                    _Float16 xh, xl; split2(hv, xh, xl);
                    nh[r] = xh; nl[r] = xl;
                }
                *(half4v*)&U[hoff] = nh;
                *(half4v*)&U[32 * HSTR + hoff] = nl;
            }
        __syncthreads();
    }

    // ---- F4 : d = W4[0:16] @ h3 ; waves 0,1 full-K (3-term), write Db ----
    if (w < 2) {
        f32x4 acc = (f32x4)(0.f);
        #pragma unroll
        for (int ks = 0; ks < 8; ks++) {
            int boff = (16 * w + lo16) * HSTR + ks * 32 + hi4 * 8;
            half8 bh = *(const half8*)&U[boff];
            half8 bl = *(const half8*)&U[32 * HSTR + boff];
            int woff = lo16 * NH + ks * 32 + hi4 * 8;
            half8 ah = *(const half8*)&W4hi[woff];
            half8 al = *(const half8*)&W4lo[woff];
            acc = MFMA16(ah, bh, acc);
            acc = MFMA16(al, bh, acc);
            acc = MFMA16(ah, bl, acc);
        }
        #pragma unroll
        for (int r = 0; r < 4; r++)
            Db[(16 * w + lo16) * 17 + 4 * hi4 + r] = acc[r];
    }
    __syncthreads();   // H (union) dead; M may be written

    // ---- backward: 2 passes x 16 elements (64 cotangent cols), f16-single ----
    #pragma unroll
    for (int p = 0; p < 2; p++) {
        // m3 = V .* d3  (single f16)
        #pragma unroll
        for (int m = 0; m < 2; m++)
            #pragma unroll
            for (int n = 0; n < 4; n++) {
                const int src = (l & 48) | (4 * n + (lo16 >> 2));
                const int kbase = 32 * w + 16 * m + 4 * hi4;
                half4v vh;
                #pragma unroll
                for (int r = 0; r < 4; r++) {
                    float g = __shfl(g3f[m][p][r], src, 64);
                    vh[r] = (_Float16)(vreg[m][r] * g);
                }
                *(half4v*)&U[(16 * n + lo16) * HSTR + kbase] = vh;
            }
        __syncthreads();

        // B3: G2 = W3^T @ m3  (single-term)
        f32x4 acc2[2][4];
        #pragma unroll
        for (int m = 0; m < 2; m++)
            #pragma unroll
            for (int n = 0; n < 4; n++) acc2[m][n] = (f32x4)(0.f);
        gemm_bwd1(W3Thi, U, w, lo16, hi4, acc2);
        __syncthreads();   // readers of m3 done

        // g2 = V + G2 (f32, exact skip) ; m2 = g2 .* d2 (f16) ; keep g2 in acc2
        #pragma unroll
        for (int m = 0; m < 2; m++)
            #pragma unroll
            for (int n = 0; n < 4; n++) {
                const int src = (l & 48) | (4 * n + (lo16 >> 2));
                const int kbase = 32 * w + 16 * m + 4 * hi4;
                half4v vh;
                #pragma unroll
                for (int r = 0; r < 4; r++) {
                    float gg2 = vreg[m][r] + acc2[m][n][r];
                    acc2[m][n][r] = gg2;
                    float g = __shfl(g2f[m][p][r], src, 64);
                    vh[r] = (_Float16)(gg2 * g);
                }
                *(half4v*)&U[(16 * n + lo16) * HSTR + kbase] = vh;
            }
        __syncthreads();

        // B2: g1tot = g2 + W2^T @ m2   (single-term, accumulate onto acc2)
        gemm_bwd1(W2Thi, U, w, lo16, hi4, acc2);
        __syncthreads();

        // m1 = g1tot .* d1  (f16)
        #pragma unroll
        for (int m = 0; m < 2; m++)
            #pragma unroll
            for (int n = 0; n < 4; n++) {
                const int src = (l & 48) | (4 * n + (lo16 >> 2));
                const int kbase = 32 * w + 16 * m + 4 * hi4;
                half4v vh;
                #pragma unroll
                for (int r = 0; r < 4; r++) {
                    float g = __shfl(g1[m][p][r], src, 64);
                    vh[r] = (_Float16)(acc2[m][n][r] * g);
                }
                *(half4v*)&U[(16 * n + lo16) * HSTR + kbase] = vh;
            }
        __syncthreads();

        // J: J_p = W1^T @ m1 ; waves 0..3 full-K (single-term), direct Jfin
        if (w < 4) {
            f32x4 accj = (f32x4)(0.f);
            #pragma unroll
            for (int ks = 0; ks < 8; ks++) {
                int boff = (16 * w + lo16) * HSTR + ks * 32 + hi4 * 8;
                half8 bh = *(const half8*)&U[boff];
                int woff = lo16 * NH + ks * 32 + hi4 * 8;
                half8 ah = *(const half8*)&W1Thi[woff];
                accj = MFMA16(ah, bh, accj);
            }
            #pragma unroll
            for (int r = 0; r < 4; r++)
                Jfin[(4 * hi4 + r) * 130 + 64 * p + 16 * w + lo16] = accj[r];
        }
        __syncthreads();
    }

    // ---- projection: wave handles 4 elements; 16-lane group per element ----
    {
        const int e = 4 * w + hi4, s = lo16;
        float acol[4];
        #pragma unroll
        for (int c = 0; c < 4; c++) acol[c] = Jfin[s * 130 + 4 * e + c];
        float dval = Db[e * 17 + s];
        #pragma unroll
        for (int c = 0; c < 4; c++) {
            float n2 = wsum16(acol[c] * acol[c]);
            float inv = (n2 > 1e-30f) ? (1.0f / sqrtf(n2)) : 0.0f;
            float q = acol[c] * inv;
            #pragma unroll
            for (int cc = c + 1; cc < 4; cc++) {
                float pj = wsum16(acol[cc] * q);
                acol[cc] -= pj * q;
            }
            float pd = wsum16(dval * q);
            dval -= pd * q;
        }
        OUT[(size_t)(ebase + e) * NS + s] = dval;
    }
}

// ---------------- f32 fallback (round-1 kernel) ----------------
__device__ __forceinline__ float dot4f(float4 a, float4 b) {
    return a.x*b.x + a.y*b.y + a.z*b.z + a.w*b.w;
}

__global__ void __launch_bounds__(256, 2)
comet_fused_f32(const float* __restrict__ Z,
                const float* __restrict__ W1,
                const float* __restrict__ W2,
                const float* __restrict__ W3,
                const float* __restrict__ W4,
                float* __restrict__ OUT)
{
    __shared__ __align__(16) float h_lds[4][4][NH];
    __shared__ __align__(16) float m_lds[4][4][NH][NC];

    const int l = threadIdx.x & 63;
    const int w = threadIdx.x >> 6;
    float (*hb)[NH]     = h_lds[w];
    float (*mb)[NH][NC] = m_lds[w];
    const int ebase = (blockIdx.x * 4 + w) * 4;

    float d1g[4][4], d2g[4][4], d3g[4][4];

    {
        float acc[4][4];
        #pragma unroll
        for (int j = 0; j < 4; j++)
            #pragma unroll
            for (int e = 0; e < 4; e++) acc[j][e] = 0.f;
        #pragma unroll
        for (int s4 = 0; s4 < 4; s4++) {
            float4 wf[4];
            #pragma unroll
            for (int j = 0; j < 4; j++)
                wf[j] = *(const float4*)&W1[(l + 64*j) * NS + s4*4];
            #pragma unroll
            for (int e = 0; e < 4; e++) {
                float4 xv = *(const float4*)&Z[(ebase + e) * NS + s4*4];
                #pragma unroll
                for (int j = 0; j < 4; j++) acc[j][e] += dot4f(wf[j], xv);
            }
        }
        #pragma unroll
        for (int j = 0; j < 4; j++)
            #pragma unroll
            for (int e = 0; e < 4; e++) {
                float a = acc[j][e];
                d1g[j][e] = siggf(a);
                hb[e][l + 64*j] = logsigf(a);
            }
    }
    __syncthreads();

#define FWD_LAYER(WPTR, GARR)                                                   \
    {                                                                           \
        float acc[4][4];                                                        \
        _Pragma("unroll")                                                       \
        for (int j = 0; j < 4; j++) {                                           \
            _Pragma("unroll")                                                   \
            for (int e = 0; e < 4; e++) acc[j][e] = 0.f;                        \
        }                                                                       \
        _Pragma("unroll 2")                                                     \
        for (int kk = 0; kk < NH; kk += 4) {                                    \
            float wv[4][4];                                                     \
            _Pragma("unroll")                                                   \
            for (int j = 0; j < 4; j++) {                                       \
                float4 t = *(const float4*)&WPTR[(l + 64*j) * NH + kk];         \
                wv[0][j] = t.x; wv[1][j] = t.y; wv[2][j] = t.z; wv[3][j] = t.w; \
            }                                                                   \
            _Pragma("unroll")                                                   \
            for (int e = 0; e < 4; e++) {                                       \
                float4 hv = *(const float4*)&hb[e][kk];                         \
                _Pragma("unroll")                                               \
                for (int j = 0; j < 4; j++)                                     \
                    acc[j][e] += wv[0][j]*hv.x + wv[1][j]*hv.y                  \
                               + wv[2][j]*hv.z + wv[3][j]*hv.w;                 \
            }                                                                   \
        }                                                                       \
        __syncthreads();                                                        \
        _Pragma("unroll")                                                       \
        for (int j = 0; j < 4; j++) {                                           \
            _Pragma("unroll")                                                   \
            for (int e = 0; e < 4; e++) {                                       \
                float a = acc[j][e];                                            \
                GARR[j][e] = siggf(a);                                          \
                hb[e][l + 64*j] += logsigf(a);                                  \
            }                                                                   \
        }                                                                       \
        __syncthreads();                                                        \
    }

    FWD_LAYER(W2, d2g)
    FWD_LAYER(W3, d3g)
#undef FWD_LAYER

    const int e4 = l >> 4, s4 = l & 15;
    float dval = 0.f;
    {
        #pragma unroll 2
        for (int kk = 0; kk < NH; kk += 4) {
            float4 wf = *(const float4*)&W4[s4 * NH + kk];
            float4 hv = *(const float4*)&hb[e4][kk];
            dval += dot4f(wf, hv);
        }
    }

    float gacc[4][4][4];
    float vf[4][4];
    #pragma unroll
    for (int c = 0; c < 4; c++)
        #pragma unroll
        for (int j = 0; j < 4; j++)
            vf[c][j] = W4[(NS + c) * NH + l + 64*j];
    #pragma unroll
    for (int e = 0; e < 4; e++)
        #pragma unroll
        for (int c = 0; c < 4; c++)
            #pragma unroll
            for (int j = 0; j < 4; j++)
                gacc[e][c][j] = vf[c][j];
    #pragma unroll
    for (int j = 0; j < 4; j++)
        #pragma unroll
        for (int e = 0; e < 4; e++) {
            float g = d3g[j][e];
            float4 mv = make_float4(vf[0][j]*g, vf[1][j]*g, vf[2][j]*g, vf[3][j]*g);
            *(float4*)&mb[e][l + 64*j][0] = mv;
        }
    __syncthreads();

#define BWD_GEMM(WPTR)                                                          \
    {                                                                           \
        _Pragma("unroll 2")                                                     \
        for (int r = 0; r < NH; r++) {                                          \
            float wc[4];                                                        \
            _Pragma("unroll")                                                   \
            for (int j = 0; j < 4; j++) wc[j] = WPTR[r * NH + l + 64*j];        \
            _Pragma("unroll")                                                   \
            for (int e = 0; e < 4; e++) {                                       \
                float4 mv = *(const float4*)&mb[e][r][0];                       \
                _Pragma("unroll")                                               \
                for (int j = 0; j < 4; j++) {                                   \
                    gacc[e][0][j] += wc[j]*mv.x;                                \
                    gacc[e][1][j] += wc[j]*mv.y;                                \
                    gacc[e][2][j] += wc[j]*mv.z;                                \
                    gacc[e][3][j] += wc[j]*mv.w;                                \
                }                                                               \
            }                                                                   \
        }                                                                       \
    }

    BWD_GEMM(W3)
    __syncthreads();
    #pragma unroll
    for (int j = 0; j < 4; j++)
        #pragma unroll
        for (int e = 0; e < 4; e++) {
            float g = d2g[j][e];
            float4 mv = make_float4(gacc[e][0][j]*g, gacc[e][1][j]*g,
                                    gacc[e][2][j]*g, gacc[e][3][j]*g);
            *(float4*)&mb[e][l + 64*j][0] = mv;
        }
    __syncthreads();
    BWD_GEMM(W2)
#undef BWD_GEMM
    __syncthreads();
    #pragma unroll
    for (int j = 0; j < 4; j++)
        #pragma unroll
        for (int e = 0; e < 4; e++) {
            float g = d1g[j][e];
            float4 mv = make_float4(gacc[e][0][j]*g, gacc[e][1][j]*g,
                                    gacc[e][2][j]*g, gacc[e][3][j]*g);
            *(float4*)&mb[e][l + 64*j][0] = mv;
        }
    __syncthreads();

    const int c4 = l >> 4;
    float jv[4] = {0.f, 0.f, 0.f, 0.f};
    #pragma unroll 4
    for (int r = 0; r < NH; r++) {
        float w1v = W1[r * NS + s4];
        #pragma unroll
        for (int e = 0; e < 4; e++) jv[e] += mb[e][r][c4] * w1v;
    }
    __syncthreads();

    float* jlds = (float*)hb;
    #pragma unroll
    for (int e = 0; e < 4; e++) jlds[e * 64 + c4 * 16 + s4] = jv[e];
    __syncthreads();

    float acol[4];
    acol[0] = jlds[e4 * 64 +      s4];
    acol[1] = jlds[e4 * 64 + 16 + s4];
    acol[2] = jlds[e4 * 64 + 32 + s4];
    acol[3] = jlds[e4 * 64 + 48 + s4];
    #pragma unroll
    for (int c = 0; c < 4; c++) {
        float n2 = wsum16(acol[c] * acol[c]);
        float inv = (n2 > 1e-30f) ? (1.0f / sqrtf(n2)) : 0.0f;
        float q = acol[c] * inv;
        #pragma unroll
        for (int cc = c + 1; cc < 4; cc++) {
            float p = wsum16(acol[cc] * q);
            acol[cc] -= p * q;
        }
        float pd = wsum16(dval * q);
        dval -= pd * q;
    }
    OUT[ebase * NS + l] = dval;
}

extern "C" void kernel_launch(void* const* d_in, const int* in_sizes, int n_in,
                              void* d_out, int out_size, void* d_ws, size_t ws_size,
                              hipStream_t stream) {
    const float* Z  = (const float*)d_in[0];
    const float* W1 = (const float*)d_in[1];
    const float* W2 = (const float*)d_in[2];
    const float* W3 = (const float*)d_in[3];
    const float* W4 = (const float*)d_in[4];
    float* OUT = (float*)d_out;

    const size_t need = (size_t)WS_HALVES * sizeof(_Float16);

    if (ws_size >= need) {
        _Float16* ws = (_Float16*)d_ws;
        hipLaunchKernelGGL(prep_big, dim3(NH, 2), dim3(NH), 0, stream, W2, W3, ws);
        hipLaunchKernelGGL(prep_small, dim3(1), dim3(NH), 0, stream, W1, W4, ws);
        hipLaunchKernelGGL(comet_mfma, dim3(BATCH / EPB), dim3(512), 0, stream,
                           Z, W4, ws, OUT);
    } else {
        hipLaunchKernelGGL(comet_fused_f32, dim3(BATCH / 16), dim3(256), 0, stream,
                           Z, W1, W2, W3, W4, OUT);
    }
}